// Round 7
// baseline (261.838 us; speedup 1.0000x reference)
//
#include <hip/hip_runtime.h>

// compute_threebody_indices for MatterSim on gfx950 — v7 (3 free-running kernels).
//
// History: v1 8-kernel 273.5 | v2 5-kernel 244.1 (best) | v3 cooperative 628 |
// v4 fence-fusion+quad-kA 256.6 | v5 fence-fusion+plainstore-kA 259.9 |
// v6b NT stores 256.3. Lessons: boundary removal pays ONLY when it adds no
// sync cost (no device-scope fences, no cooperative launch); NT stores and
// kA micro-rewrites are neutral-to-negative.
//
// v7 = v2 structure minus two dispatch boundaries, zero added sync:
//  - k0 deleted: kA uses v5's HW-verified plain-store degree (unique run-tail
//    thread counts whole run; backward walk for rare wave-spanning runs) and
//    run-head threads zero gap (bondless) atoms. No atomics, no init pass.
//  - kC deleted: kB leaves bsums as RAW tile totals; each kD wave derives
//    sum(bsums[0..tile)) with 2 guarded loads + 6-step shfl_xor reduction
//    (98 tiles, L2-hot); kD block 0 wave 0 emits n_triple_s the same way.
//    Ordering comes free from the kB->kD dispatch boundary.
//
// Outputs (int32, concatenated flat in d_out):
//   [0, 2T)                       bond_indices [T,2]  (pairs of ORIGINAL bond ids)
//   [2T, 2T+n_bond)               n_triple_ij
//   [.., +n_atom)                 n_triple_i
//   [.., +n_struct)               n_triple_s

#define CUTOFF 0.8f
#define NATOM_C 100000
#define MAXD 256   // max kept bonds per atom; actual max ~45 (Poisson mean ~16)

// ---- KA: segment bounds + kept-degree (plain stores, no atomics, no init) ----
// Sorted src => runs contiguous. The unique run-tail thread counts kept bonds
// of the ENTIRE run: in-wave part via masked ballot popcount; if the run
// extends before this wave, a backward global walk (L1/L2-hot, <= run length)
// adds the rest. Run-head threads zero bondless gap atoms. [HW-verified in v5]
__global__ void kA_bounds_deg(const int* __restrict__ src, const float* __restrict__ len,
                              int* __restrict__ wstart, int* __restrict__ wend,
                              int* __restrict__ deg, int n_bond, int n_atom) {
    int i = blockIdx.x * blockDim.x + threadIdx.x;
    int lane = threadIdx.x & 63;
    bool valid = i < n_bond;
    int a = -1; bool kept = false;
    if (valid) { a = src[i]; kept = (len[i] <= CUTOFF); }

    // neighbor atoms (all lanes participate in shuffles; edges load global)
    int ap = __shfl_up(a, 1);
    if (lane == 0) ap = (valid && i > 0) ? src[i - 1] : -1;
    int an = __shfl_down(a, 1);
    if (lane == 63) an = (valid && i + 1 < n_bond) ? src[i + 1] : -2;

    bool head = valid && (i == 0 || ap != a);
    bool tail = valid && (i == n_bond - 1 || an != a);

    unsigned long long keptB = __ballot(kept);
    unsigned long long headB = __ballot(head);

    if (head) {
        wstart[a] = i;
        // zero bondless atoms in the gap (prev_atom, a) — ~never taken here
        int p = (i == 0) ? -1 : ap;
        for (int g = p + 1; g < a; ++g) { wstart[g] = 0; wend[g] = 0; deg[g] = 0; }
    }
    if (tail) {
        wend[a] = i + 1;
        if (i == n_bond - 1)             // trailing gap at the very end
            for (int g = a + 1; g < n_atom; ++g) { wstart[g] = 0; wend[g] = 0; deg[g] = 0; }

        // count kept bonds of the whole run
        unsigned long long belowInc = (lane == 63) ? ~0ull : ((2ull << lane) - 1ull);
        unsigned long long h = headB & belowInc;
        int cnt;
        if (h) {                          // run starts within this wave
            int runStartLane = 63 - __clzll(h);
            unsigned long long runMask = belowInc & ~((1ull << runStartLane) - 1ull);
            cnt = __popcll(keptB & runMask);
        } else {                          // run extends before the wave: walk back
            cnt = __popcll(keptB & belowInc);
            int wbase = i - lane;         // wave's first global index
            for (int j = wbase - 1; j >= 0; --j) {
                if (src[j] != a) break;
                if (len[j] <= CUTOFF) cnt++;
            }
        }
        deg[a] = cnt;                     // plain store: exactly one tail per run
    }
}

// ---- KB: per-tile (1024 atoms) exclusive scan of d*(d-1); n_triple_i out.
//          bsums keeps RAW tile totals (kD derives prefixes itself). ----
__global__ void kB_scan(const int* __restrict__ deg, int* __restrict__ out_i,
                        int* __restrict__ exsc, int* __restrict__ bsums, int n) {
    __shared__ int tmp[256];
    int t = threadIdx.x;
    int base = blockIdx.x * 1024 + t * 4;
    int v0 = 0, v1 = 0, v2 = 0, v3 = 0;
    if (base + 3 < n) {
        int4 d4 = *(const int4*)(deg + base);
        v0 = d4.x * (d4.x - 1); v1 = d4.y * (d4.y - 1);
        v2 = d4.z * (d4.z - 1); v3 = d4.w * (d4.w - 1);
        *(int4*)(out_i + base) = make_int4(v0, v1, v2, v3);
    } else {
        if (base     < n) { int d = deg[base];     v0 = d * (d - 1); out_i[base]     = v0; }
        if (base + 1 < n) { int d = deg[base + 1]; v1 = d * (d - 1); out_i[base + 1] = v1; }
        if (base + 2 < n) { int d = deg[base + 2]; v2 = d * (d - 1); out_i[base + 2] = v2; }
        if (base + 3 < n) { int d = deg[base + 3]; v3 = d * (d - 1); out_i[base + 3] = v3; }
    }
    int s = v0 + v1 + v2 + v3;
    tmp[t] = s;
    __syncthreads();
    for (int off = 1; off < 256; off <<= 1) {
        int v = (t >= off) ? tmp[t - off] : 0;
        __syncthreads();
        tmp[t] += v;
        __syncthreads();
    }
    int excl = tmp[t] - s;                       // exclusive prefix within tile
    if (base     < n) exsc[base]     = excl;
    if (base + 1 < n) exsc[base + 1] = excl + v0;
    if (base + 2 < n) exsc[base + 2] = excl + v0 + v1;
    if (base + 3 < n) exsc[base + 3] = excl + v0 + v1 + v2;
    if (t == 255) bsums[blockIdx.x] = tmp[255];  // RAW tile total
}

// wave-uniform sum of bsums[0..K) (K <= ~128: <=2 loads/lane + butterfly)
__device__ __forceinline__ int wave_prefix_sum(const int* __restrict__ bsums,
                                               int K, int lane) {
    int x = 0;
    for (int l = lane; l < K; l += 64) x += bsums[l];
#pragma unroll
    for (int m = 1; m < 64; m <<= 1) x += __shfl_xor(x, m);
    return x;    // same value in all 64 lanes
}

// ---- KD: wave-per-atom triple enumeration + n_triple_ij (4 atoms / block);
//          per-wave bsums reduction replaces kC; block 0 emits n_triple_s ----
__global__ void kD_enum(const float* __restrict__ len, const int* __restrict__ wstart,
                        const int* __restrict__ wend, const int* __restrict__ exsc,
                        const int* __restrict__ bsums, const int* __restrict__ n_atoms_arr,
                        int4* __restrict__ out4, int* __restrict__ out_ij,
                        int* __restrict__ out_s,
                        int n_atom, int ntiles, int n_struct) {
    __shared__ int keptIds[4 * MAXD];
    int wave = threadIdx.x >> 6;
    int lane = threadIdx.x & 63;
    int a = blockIdx.x * 4 + wave;
    int* my = &keptIds[wave * MAXD];

    // ---- n_triple_s (block 0, wave 0 only; bsums/exsc ready via boundary) ----
    if (blockIdx.x == 0 && wave == 0) {
        int off = 0, prevA = 0;
        for (int s2 = 0; s2 < n_struct; s2++) {
            off += n_atoms_arr[s2];
            int A;
            if (off >= n_atom) A = wave_prefix_sum(bsums, ntiles, lane);
            else               A = wave_prefix_sum(bsums, off >> 10, lane) + exsc[off];
            if (lane == 0) out_s[s2] = A - prevA;
            prevA = A;
        }
    }

    if (a >= n_atom) return;
    int s = wstart[a], e = wend[a];
    int d = 0;
    unsigned long long bal[4] = {0ull, 0ull, 0ull, 0ull};
    // order-preserving compaction of kept ORIGINAL bond ids into LDS
#pragma unroll
    for (int it = 0; it < 4; ++it) {             // static indices -> registers
        int base = s + it * 64;
        if (base < e) {
            int idx = base + lane;
            bool m = (idx < e) && (len[idx] <= CUTOFF);
            unsigned long long b = __ballot(m);
            bal[it] = b;
            int pos = d + __popcll(b & ((1ull << lane) - 1ull));
            if (m && pos < MAXD) my[pos] = idx;
            d += __popcll(b);
        }
    }
    for (int base = s + 256; base < e; base += 64) {   // cold path (d>256 never)
        int idx = base + lane;
        bool m = (idx < e) && (len[idx] <= CUTOFF);
        unsigned long long b = __ballot(m);
        int pos = d + __popcll(b & ((1ull << lane) - 1ull));
        if (m && pos < MAXD) my[pos] = idx;
        d += __popcll(b);
    }
    int dm1 = d - 1;
#pragma unroll
    for (int it = 0; it < 4; ++it) {
        int idx = s + it * 64 + lane;
        if (idx < e) out_ij[idx] = ((bal[it] >> lane) & 1ull) ? dm1 : 0;
    }
    for (int base = s + 256; base < e; base += 64) {   // cold path
        int idx = base + lane;
        if (idx < e) out_ij[idx] = (len[idx] <= CUTOFF) ? dm1 : 0;
    }
    if (d >= 2) {
        // tstart[a] = exsc[a] + sum of raw tile totals before a's tile
        int pref = wave_prefix_sum(bsums, a >> 10, lane);
        int b4 = (exsc[a] + pref) >> 1;                  // tstart[a]/2, exact
        unsigned udm1 = (unsigned)dm1;
        unsigned nP = ((unsigned)(d * dm1)) >> 1;        // pairs of triples
        for (unsigned p = lane; p < nP; p += 64) {
            unsigned t0 = 2u * p;
            unsigned j  = t0 / udm1;                     // one div per PAIR
            unsigned kp = t0 - j * udm1;
            unsigned j1 = j, kp1 = kp + 1;
            if (kp1 == udm1) { j1++; kp1 = 0; }          // t0+1 rollover
            unsigned k0 = kp  + (kp  >= j  ? 1u : 0u);   // skip k == j
            unsigned k1 = kp1 + (kp1 >= j1 ? 1u : 0u);
            out4[b4 + p] = make_int4(my[j], my[k0], my[j1], my[k1]);
        }
    }
}

// ================================ launch ================================
extern "C" void kernel_launch(void* const* d_in, const int* in_sizes, int n_in,
                              void* d_out, int out_size, void* d_ws, size_t ws_size,
                              hipStream_t stream) {
    const int*   bond_src    = (const int*)d_in[0];
    const float* bond_len    = (const float*)d_in[1];
    const int*   n_atoms_arr = (const int*)d_in[2];
    int n_bond   = in_sizes[0];
    int n_struct = in_sizes[2];
    const int n_atom = NATOM_C;
    int T2 = out_size - n_bond - n_atom - n_struct;   // = 2*T

    int ntiles = (n_atom + 1023) / 1024;              // 98

    // workspace (ints): wstart | wend | deg | exsc[n_atom] | bsums[ntiles]
    int* ws     = (int*)d_ws;
    int* wstart = ws;
    int* wend   = ws + n_atom;
    int* deg    = ws + 2 * n_atom;
    int* exsc   = ws + 3 * n_atom;
    int* bsums  = exsc + n_atom;

    int*  out       = (int*)d_out;
    int4* out_pairs = (int4*)out;          // [T/2] rows of 2 triples, 16B-aligned
    int*  out_ij    = out + T2;
    int*  out_i     = out_ij + n_bond;
    int*  out_s     = out_i + n_atom;

    kA_bounds_deg<<<(n_bond + 255) / 256, 256, 0, stream>>>(bond_src, bond_len, wstart, wend,
                                                            deg, n_bond, n_atom);
    kB_scan      <<<ntiles, 256, 0, stream>>>(deg, out_i, exsc, bsums, n_atom);
    kD_enum      <<<(n_atom + 3) / 4, 256, 0, stream>>>(bond_len, wstart, wend, exsc, bsums,
                                                        n_atoms_arr, out_pairs, out_ij, out_s,
                                                        n_atom, ntiles, n_struct);
}